// Round 9
// baseline (333.824 us; speedup 1.0000x reference)
//
#include <hip/hip_runtime.h>
#include <hip/hip_bf16.h>

#define MUL_Sc 256
#define DIM_Hc 640
#define IN_COLS 644
#define KF 768
#define NT 32
#define GRIDB 256

#define C0F 0.05103103630798287f
#define INV_SQRT3F 0.57735026918962576f

typedef __attribute__((ext_vector_type(8))) short short8;
typedef __attribute__((ext_vector_type(4))) float f32x4;

#define MFMA(a, b, c) __builtin_amdgcn_mfma_f32_16x16x32_bf16((a), (b), (c), 0, 0, 0)

__device__ __forceinline__ unsigned short f2bf(float x) {
    union { float f; unsigned u; } v; v.f = x;
    unsigned r = v.u + 0x7fffu + ((v.u >> 16) & 1u);   // RNE
    return (unsigned short)(r >> 16);
}

// ---- weight prep: fp32 [k][col] -> bf16 transposed [col][k] (proven numerics) ----
// WT_sg 384x384: cols 0..255 scal (k<256: Wss, k>=256: Wvv), cols 256..383 gate (Wssg/Wvvg)
// WT_sv 128x256, WT_vs 128x128
__global__ void prep_weights(const float* __restrict__ Wss, const float* __restrict__ Wvv,
                             const float* __restrict__ Wssg, const float* __restrict__ Wvvg,
                             const float* __restrict__ Wsv, const float* __restrict__ Wvs,
                             unsigned short* __restrict__ wt) {
    int i = blockIdx.x * 256 + threadIdx.x;
    const int N_SG = 384 * 384;
    const int N_SV = 128 * 256;
    const int N_VS = 128 * 128;
    if (i < N_SG) {
        int col = i / 384, k = i % 384;
        float v;
        if (col < 256) v = (k < 256) ? Wss[k * 256 + col] : Wvv[(k - 256) * 256 + col];
        else { int c = col - 256; v = (k < 256) ? Wssg[k * 128 + c] : Wvvg[(k - 256) * 128 + c]; }
        wt[i] = f2bf(v);
    } else if (i < N_SG + N_SV) {
        int j = i - N_SG; int col = j >> 8, k = j & 255;
        wt[i] = f2bf(Wsv[k * 128 + col]);
    } else if (i < N_SG + N_SV + N_VS) {
        int j = i - N_SG - N_SV; int col = j >> 7, k = j & 127;
        wt[i] = f2bf(Wvs[k * 128 + col]);
    }
}

// ---- persistent producer/consumer kernel ----
// feat row per node (bf16, 768): [ xs(0:256) | dot(256:384) | xv_k0(384:512) | xv_k1(512:640) | xv_k2(640:768) ]
// waves 0..3 = consumers (MFMA + epilogues), waves 4..7 = producers (stage din -> feat)
__global__ __launch_bounds__(512, 2)
void fused_main(const float* __restrict__ din, const unsigned short* __restrict__ wt,
                const float* __restrict__ bias, float* __restrict__ out,
                int N, int ntiles) {
    __shared__ unsigned short feat[2][NT * KF];   // 2 x 48 KB
    __shared__ float psv[2][NT * 4];

    const int tid  = threadIdx.x;
    const bool prod = tid >= 256;
    const int ptid = tid & 255;

    const unsigned short* WTsg = wt;
    const unsigned short* WTsv = wt + 384 * 384;
    const unsigned short* WTvs = wt + 384 * 384 + 128 * 256;

    // ---------- consumer constants ----------
    const int cw    = tid >> 6;          // 0..3 for consumers
    const int lane  = tid & 63;
    const int l15   = lane & 15;
    const int lkb   = (lane >> 4) << 3;
    const int rbase = (lane >> 4) << 2;
    const int swzr  = (l15 & 7) << 4;

    float bcs[4];
    if (!prod) {
        #pragma unroll
        for (int t = 0; t < 4; ++t) bcs[t] = bias[(t * 4 + cw) * 16 + l15];
    }

    // ---------- producer staging: R7-proven 16-threads-per-node math, 2 passes ----------
    auto stage_tile = [&](int tile, int wb) {
        char* fb = (char*)&feat[wb][0];
        #pragma unroll
        for (int h = 0; h < 2; ++h) {
            const int g = h * 16 + (ptid >> 4);   // local node 0..31
            const int j = ptid & 15;
            int n = tile * NT + g; if (n >= N) n = N - 1;
            const float* row = din + (size_t)n * IN_COLS;
            float ps  = row[DIM_Hc];
            float pv0 = row[DIM_Hc + 1], pv1 = row[DIM_Hc + 2], pv2 = row[DIM_Hc + 3];
            if (j == 0) {
                psv[wb][g*4+0] = ps; psv[wb][g*4+1] = pv0;
                psv[wb][g*4+2] = pv1; psv[wb][g*4+3] = pv2;
            }
            const int swz  = (g & 7) << 4;
            const int rowb = g * (KF * 2);

            // xs: 16 consecutive elems per thread -> 2x b128 writes
            {
                int c = 16 * j;
                float4 x0 = *(const float4*)(row + c);
                float4 x1 = *(const float4*)(row + c + 4);
                float4 x2 = *(const float4*)(row + c + 8);
                float4 x3 = *(const float4*)(row + c + 12);
                short8 p0, p1;
                p0[0]=(short)f2bf(x0.x); p0[1]=(short)f2bf(x0.y); p0[2]=(short)f2bf(x0.z); p0[3]=(short)f2bf(x0.w);
                p0[4]=(short)f2bf(x1.x); p0[5]=(short)f2bf(x1.y); p0[6]=(short)f2bf(x1.z); p0[7]=(short)f2bf(x1.w);
                p1[0]=(short)f2bf(x2.x); p1[1]=(short)f2bf(x2.y); p1[2]=(short)f2bf(x2.z); p1[3]=(short)f2bf(x2.w);
                p1[4]=(short)f2bf(x3.x); p1[5]=(short)f2bf(x3.y); p1[6]=(short)f2bf(x3.z); p1[7]=(short)f2bf(x3.w);
                *(short8*)(fb + ((rowb + c * 2) ^ swz))       = p0;
                *(short8*)(fb + ((rowb + (c + 8) * 2) ^ swz)) = p1;
            }
            // xv: 8 consecutive u per thread (24 floats) -> dot + 3 k-planes, b128 each
            {
                int u0 = 8 * j;
                const float* p = row + MUL_Sc + 3 * u0;
                float e[24];
                #pragma unroll
                for (int q = 0; q < 6; ++q) {
                    float4 v = *(const float4*)(p + 4 * q);
                    e[4*q+0] = v.x; e[4*q+1] = v.y; e[4*q+2] = v.z; e[4*q+3] = v.w;
                }
                short8 dp, k0, k1, k2;
                #pragma unroll
                for (int m = 0; m < 8; ++m) {
                    float a = e[3*m], b = e[3*m+1], c = e[3*m+2];
                    dp[m] = (short)f2bf((a * pv0 + b * pv1 + c * pv2) * INV_SQRT3F);
                    k0[m] = (short)f2bf(a);
                    k1[m] = (short)f2bf(b);
                    k2[m] = (short)f2bf(c);
                }
                *(short8*)(fb + ((rowb + (256 + u0) * 2) ^ swz)) = dp;
                *(short8*)(fb + ((rowb + (384 + u0) * 2) ^ swz)) = k0;
                *(short8*)(fb + ((rowb + (512 + u0) * 2) ^ swz)) = k1;
                *(short8*)(fb + ((rowb + (640 + u0) * 2) ^ swz)) = k2;
            }
        }
    };

    // ---------- prologue: stage first tile into buffer 0 ----------
    if (prod) stage_tile(blockIdx.x, 0);
    __syncthreads();

    int wbuf = 0;
    for (int tile = blockIdx.x; tile < ntiles; tile += GRIDB) {
        if (prod) {
            int nx = tile + GRIDB;
            if (nx < ntiles) stage_tile(nx, wbuf ^ 1);
        } else {
            // ================= consumer compute for tile =================
            const char* fbr = (const char*)&feat[wbuf][0];
            const float* pvv = &psv[wbuf][0];
            const int n0 = tile * NT;

            float pss[2][4];
            #pragma unroll
            for (int m = 0; m < 2; ++m)
            #pragma unroll
            for (int i = 0; i < 4; ++i) pss[m][i] = pvv[(m * 16 + rbase + i) * 4];

            // ---- sg GEMM: 6 col-tiles (t=0..3 scal, t=4..5 gate) ----
            f32x4 accS[6][2];
            #pragma unroll
            for (int t = 0; t < 6; ++t) { accS[t][0] = (f32x4){0,0,0,0}; accS[t][1] = (f32x4){0,0,0,0}; }

            #pragma unroll
            for (int ks = 0; ks < 8; ++ks) {    // xs part K=256
                int kf = ks * 32 + lkb;
                short8 a0 = *(const short8*)(fbr + ((l15 * 1536 + kf * 2) ^ swzr));
                short8 a1 = *(const short8*)(fbr + (((16 + l15) * 1536 + kf * 2) ^ swzr));
                #pragma unroll
                for (int t = 0; t < 6; ++t) {
                    int col = (t * 4 + cw) * 16 + l15;
                    short8 b = *(const short8*)(WTsg + col * 384 + ks * 32 + lkb);
                    accS[t][0] = MFMA(a0, b, accS[t][0]);
                    accS[t][1] = MFMA(a1, b, accS[t][1]);
                }
            }
            #pragma unroll
            for (int t = 0; t < 6; ++t)
            #pragma unroll
            for (int m = 0; m < 2; ++m)
            #pragma unroll
            for (int i = 0; i < 4; ++i) accS[t][m][i] *= pss[m][i];
            #pragma unroll
            for (int ks = 0; ks < 4; ++ks) {    // dot part K=128
                int kf = 256 + ks * 32 + lkb;
                short8 a0 = *(const short8*)(fbr + ((l15 * 1536 + kf * 2) ^ swzr));
                short8 a1 = *(const short8*)(fbr + (((16 + l15) * 1536 + kf * 2) ^ swzr));
                #pragma unroll
                for (int t = 0; t < 6; ++t) {
                    int col = (t * 4 + cw) * 16 + l15;
                    short8 b = *(const short8*)(WTsg + col * 384 + 256 + ks * 32 + lkb);
                    accS[t][0] = MFMA(a0, b, accS[t][0]);
                    accS[t][1] = MFMA(a1, b, accS[t][1]);
                }
            }

            // ---- scal epilogue: silu -> global ----
            #pragma unroll
            for (int t = 0; t < 4; ++t) {
                int col = (t * 4 + cw) * 16 + l15;
                #pragma unroll
                for (int m = 0; m < 2; ++m)
                #pragma unroll
                for (int i = 0; i < 4; ++i) {
                    int n = n0 + m * 16 + rbase + i;
                    if (n < N) {
                        float sc = C0F * accS[t][m][i] + bcs[t];
                        out[(size_t)n * DIM_Hc + col] = sc / (1.f + __expf(-sc));
                    }
                }
            }
            // gate -> sigmoid in registers (same lane computes matching u-tile s*4+cw)
            float sgr[2][2][4];
            #pragma unroll
            for (int s = 0; s < 2; ++s)
            #pragma unroll
            for (int m = 0; m < 2; ++m)
            #pragma unroll
            for (int i = 0; i < 4; ++i) sgr[s][m][i] = 1.f / (1.f + __expf(-C0F * accS[4 + s][m][i]));

            // ---- vec GEMMs: a1 (xs, K=256) + v2_k (xv planes, K=128 x3), 2 u-tiles ----
            f32x4 accA[2][2], accV[3][2][2];
            #pragma unroll
            for (int s = 0; s < 2; ++s) {
                accA[s][0] = (f32x4){0,0,0,0}; accA[s][1] = (f32x4){0,0,0,0};
                #pragma unroll
                for (int k = 0; k < 3; ++k) { accV[k][s][0] = (f32x4){0,0,0,0}; accV[k][s][1] = (f32x4){0,0,0,0}; }
            }
            #pragma unroll
            for (int ks = 0; ks < 8; ++ks) {
                int kf = ks * 32 + lkb;
                short8 a0 = *(const short8*)(fbr + ((l15 * 1536 + kf * 2) ^ swzr));
                short8 a1 = *(const short8*)(fbr + (((16 + l15) * 1536 + kf * 2) ^ swzr));
                #pragma unroll
                for (int s = 0; s < 2; ++s) {
                    int ucol = (s * 4 + cw) * 16 + l15;
                    short8 b = *(const short8*)(WTsv + ucol * 256 + ks * 32 + lkb);
                    accA[s][0] = MFMA(a0, b, accA[s][0]);
                    accA[s][1] = MFMA(a1, b, accA[s][1]);
                }
            }
            #pragma unroll
            for (int ks = 0; ks < 4; ++ks) {
                short8 bv[2];
                #pragma unroll
                for (int s = 0; s < 2; ++s)
                    bv[s] = *(const short8*)(WTvs + ((s * 4 + cw) * 16 + l15) * 128 + ks * 32 + lkb);
                #pragma unroll
                for (int p = 0; p < 3; ++p) {
                    int kf = 384 + 128 * p + ks * 32 + lkb;
                    short8 a0 = *(const short8*)(fbr + ((l15 * 1536 + kf * 2) ^ swzr));
                    short8 a1 = *(const short8*)(fbr + (((16 + l15) * 1536 + kf * 2) ^ swzr));
                    #pragma unroll
                    for (int s = 0; s < 2; ++s) {
                        accV[p][s][0] = MFMA(a0, bv[s], accV[p][s][0]);
                        accV[p][s][1] = MFMA(a1, bv[s], accV[p][s][1]);
                    }
                }
            }

            // ---- vec epilogue: vec = C0*(a1*pv + v2*ps) * sigmoid(gate) ----
            #pragma unroll
            for (int s = 0; s < 2; ++s) {
                int u = (s * 4 + cw) * 16 + l15;
                #pragma unroll
                for (int m = 0; m < 2; ++m)
                #pragma unroll
                for (int i = 0; i < 4; ++i) {
                    int nl = m * 16 + rbase + i;
                    int n = n0 + nl;
                    if (n >= N) continue;
                    float sg  = sgr[s][m][i];
                    float ps  = pss[m][i];
                    float pv0 = pvv[nl * 4 + 1], pv1 = pvv[nl * 4 + 2], pv2 = pvv[nl * 4 + 3];
                    float av = accA[s][m][i];
                    size_t ob = (size_t)n * DIM_Hc + MUL_Sc + 3 * u;
                    out[ob + 0] = C0F * (av * pv0 + accV[0][s][m][i] * ps) * sg;
                    out[ob + 1] = C0F * (av * pv1 + accV[1][s][m][i] * ps) * sg;
                    out[ob + 2] = C0F * (av * pv2 + accV[2][s][m][i] * ps) * sg;
                }
            }
        }
        __syncthreads();
        wbuf ^= 1;
    }
}

extern "C" void kernel_launch(void* const* d_in, const int* in_sizes, int n_in,
                              void* d_out, int out_size, void* d_ws, size_t ws_size,
                              hipStream_t stream) {
    const float* din  = (const float*)d_in[0];
    const float* Wss  = (const float*)d_in[1];
    const float* Wvv  = (const float*)d_in[2];
    const float* Wssg = (const float*)d_in[3];
    const float* Wvvg = (const float*)d_in[4];
    const float* Wsv  = (const float*)d_in[5];
    const float* Wvs  = (const float*)d_in[6];
    const float* bias = (const float*)d_in[7];
    float* out = (float*)d_out;
    unsigned short* wt = (unsigned short*)d_ws;

    const size_t WT_BYTES = (size_t)(384 * 384 + 128 * 256 + 128 * 128) * 2;
    if (ws_size < WT_BYTES) return;

    int N = in_sizes[0] / IN_COLS;
    int ntiles = (N + NT - 1) / NT;

    int prep_total = 384 * 384 + 128 * 256 + 128 * 128;
    prep_weights<<<(prep_total + 255) / 256, 256, 0, stream>>>(Wss, Wvv, Wssg, Wvvg, Wsv, Wvs, wt);

    fused_main<<<GRIDB, 512, 0, stream>>>(din, wt, bias, out, N, ntiles);
}

// Round 12
// 234.514 us; speedup vs baseline: 1.4235x; 1.4235x over previous
//
#include <hip/hip_runtime.h>
#include <hip/hip_bf16.h>

#define MUL_Sc 256
#define DIM_Hc 640
#define IN_COLS 644
#define KF 768
#define NT 64

#define C0F 0.05103103630798287f
#define INV_SQRT3F 0.57735026918962576f

typedef __attribute__((ext_vector_type(8))) short short8;
typedef __attribute__((ext_vector_type(4))) float f32x4;

#define MFMA(a, b, c) __builtin_amdgcn_mfma_f32_16x16x32_bf16((a), (b), (c), 0, 0, 0)

__device__ __forceinline__ unsigned short f2bf(float x) {
    union { float f; unsigned u; } v; v.f = x;
    unsigned r = v.u + 0x7fffu + ((v.u >> 16) & 1u);   // RNE
    return (unsigned short)(r >> 16);
}

// ---- weight prep: fp32 [k][col] -> bf16 transposed [col][k] (proven numerics) ----
// WT_sg 384x384: cols 0..255 scal (k<256: Wss, k>=256: Wvv), cols 256..383 gate (Wssg/Wvvg)
// WT_sv 128x256, WT_vs 128x128
__global__ void prep_weights(const float* __restrict__ Wss, const float* __restrict__ Wvv,
                             const float* __restrict__ Wssg, const float* __restrict__ Wvvg,
                             const float* __restrict__ Wsv, const float* __restrict__ Wvs,
                             unsigned short* __restrict__ wt) {
    int i = blockIdx.x * 256 + threadIdx.x;
    const int N_SG = 384 * 384;
    const int N_SV = 128 * 256;
    const int N_VS = 128 * 128;
    if (i < N_SG) {
        int col = i / 384, k = i % 384;
        float v;
        if (col < 256) v = (k < 256) ? Wss[k * 256 + col] : Wvv[(k - 256) * 256 + col];
        else { int c = col - 256; v = (k < 256) ? Wssg[k * 128 + c] : Wvvg[(k - 256) * 128 + c]; }
        wt[i] = f2bf(v);
    } else if (i < N_SG + N_SV) {
        int j = i - N_SG; int col = j >> 8, k = j & 255;
        wt[i] = f2bf(Wsv[k * 128 + col]);
    } else if (i < N_SG + N_SV + N_VS) {
        int j = i - N_SG - N_SV; int col = j >> 7, k = j & 127;
        wt[i] = f2bf(Wvs[k * 128 + col]);
    }
}

// ---- fused main kernel: NT=64, single barrier, gate in registers ----
// feat row per node (bf16, 768): [ xs(0:256) | dot(256:384) | xv_k0(384:512) | xv_k1(512:640) | xv_k2(640:768) ]
__global__ __launch_bounds__(512, 2)
void fused_main(const float* __restrict__ din, const unsigned short* __restrict__ wt,
                const float* __restrict__ bias, float* __restrict__ out, int N) {
    __shared__ unsigned short feat[NT * KF];   // 96 KB, XOR-swizzled: byte ^= (node&7)<<4
    __shared__ float psv[NT * 4];

    const int tid = threadIdx.x;
    const int n0 = blockIdx.x * NT;

    // ---------------- staging: 8 threads per node ----------------
    {
        const int g = tid >> 3;       // local node 0..63
        const int j = tid & 7;
        int n = n0 + g; if (n >= N) n = N - 1;
        const float* row = din + (size_t)n * IN_COLS;
        float ps  = row[DIM_Hc];
        float pv0 = row[DIM_Hc + 1], pv1 = row[DIM_Hc + 2], pv2 = row[DIM_Hc + 3];
        if (j == 0) { psv[g*4+0] = ps; psv[g*4+1] = pv0; psv[g*4+2] = pv1; psv[g*4+3] = pv2; }
        char* fb = (char*)feat;
        const int swz  = (g & 7) << 4;
        const int rowb = g * (KF * 2);

        // xs: 32 consecutive elems per thread -> 4x b128 writes (two R5-style passes)
        #pragma unroll
        for (int half = 0; half < 2; ++half) {
            int c = 32 * j + 16 * half;
            float4 x0 = *(const float4*)(row + c);
            float4 x1 = *(const float4*)(row + c + 4);
            float4 x2 = *(const float4*)(row + c + 8);
            float4 x3 = *(const float4*)(row + c + 12);
            short8 p0, p1;
            p0[0]=(short)f2bf(x0.x); p0[1]=(short)f2bf(x0.y); p0[2]=(short)f2bf(x0.z); p0[3]=(short)f2bf(x0.w);
            p0[4]=(short)f2bf(x1.x); p0[5]=(short)f2bf(x1.y); p0[6]=(short)f2bf(x1.z); p0[7]=(short)f2bf(x1.w);
            p1[0]=(short)f2bf(x2.x); p1[1]=(short)f2bf(x2.y); p1[2]=(short)f2bf(x2.z); p1[3]=(short)f2bf(x2.w);
            p1[4]=(short)f2bf(x3.x); p1[5]=(short)f2bf(x3.y); p1[6]=(short)f2bf(x3.z); p1[7]=(short)f2bf(x3.w);
            *(short8*)(fb + ((rowb + c * 2) ^ swz))       = p0;
            *(short8*)(fb + ((rowb + (c + 8) * 2) ^ swz)) = p1;
        }
        // xv: 16 consecutive u per thread (two R5-style passes of 8 u)
        #pragma unroll
        for (int half = 0; half < 2; ++half) {
            int u0 = 16 * j + 8 * half;
            const float* p = row + MUL_Sc + 3 * u0;
            float e[24];
            #pragma unroll
            for (int q = 0; q < 6; ++q) {
                float4 v = *(const float4*)(p + 4 * q);
                e[4*q+0] = v.x; e[4*q+1] = v.y; e[4*q+2] = v.z; e[4*q+3] = v.w;
            }
            short8 dp, k0, k1, k2;
            #pragma unroll
            for (int m = 0; m < 8; ++m) {
                float a = e[3*m], b = e[3*m+1], c = e[3*m+2];
                dp[m] = (short)f2bf((a * pv0 + b * pv1 + c * pv2) * INV_SQRT3F);
                k0[m] = (short)f2bf(a);
                k1[m] = (short)f2bf(b);
                k2[m] = (short)f2bf(c);
            }
            *(short8*)(fb + ((rowb + (256 + u0) * 2) ^ swz)) = dp;
            *(short8*)(fb + ((rowb + (384 + u0) * 2) ^ swz)) = k0;
            *(short8*)(fb + ((rowb + (512 + u0) * 2) ^ swz)) = k1;
            *(short8*)(fb + ((rowb + (640 + u0) * 2) ^ swz)) = k2;
        }
    }
    __syncthreads();   // the ONLY barrier

    const int wave = tid >> 6;            // 0..7
    const int lane = tid & 63;
    const int l15  = lane & 15;
    const int lkb  = (lane >> 4) << 3;    // k sub-offset: 0,8,16,24
    const int rbase = (lane >> 4) << 2;
    const char* fbr = (const char*)feat;
    const int swzr = (l15 & 7) << 4;

    const unsigned short* WTsg = wt;
    const unsigned short* WTsv = wt + 384 * 384;
    const unsigned short* WTvs = wt + 384 * 384 + 128 * 256;

    float pss[4][4];
    #pragma unroll
    for (int m = 0; m < 4; ++m)
    #pragma unroll
    for (int i = 0; i < 4; ++i) pss[m][i] = psv[(m * 16 + rbase + i) * 4];

    // ---------------- sg GEMM: t=0,1 scal col-tiles, t=2 gate col-tile; 4 m-subtiles ----------------
    f32x4 accS[3][4];
    #pragma unroll
    for (int t = 0; t < 3; ++t)
    #pragma unroll
    for (int m = 0; m < 4; ++m) accS[t][m] = (f32x4){0,0,0,0};

    #pragma unroll
    for (int ks = 0; ks < 8; ++ks) {      // xs part K=256
        int kf = ks * 32 + lkb;
        short8 a[4];
        #pragma unroll
        for (int m = 0; m < 4; ++m)
            a[m] = *(const short8*)(fbr + (((m * 16 + l15) * 1536 + kf * 2) ^ swzr));
        #pragma unroll
        for (int t = 0; t < 3; ++t) {
            int ct = wave + t * 8;        // t=2 -> cols 256+wave*16 (gate)
            short8 b = *(const short8*)(WTsg + (ct * 16 + l15) * 384 + ks * 32 + lkb);
            #pragma unroll
            for (int m = 0; m < 4; ++m) accS[t][m] = MFMA(a[m], b, accS[t][m]);
        }
    }
    #pragma unroll
    for (int t = 0; t < 3; ++t)
    #pragma unroll
    for (int m = 0; m < 4; ++m)
    #pragma unroll
    for (int i = 0; i < 4; ++i) accS[t][m][i] *= pss[m][i];
    #pragma unroll
    for (int ks = 0; ks < 4; ++ks) {      // dot part K=128
        int kf = 256 + ks * 32 + lkb;
        short8 a[4];
        #pragma unroll
        for (int m = 0; m < 4; ++m)
            a[m] = *(const short8*)(fbr + (((m * 16 + l15) * 1536 + kf * 2) ^ swzr));
        #pragma unroll
        for (int t = 0; t < 3; ++t) {
            int ct = wave + t * 8;
            short8 b = *(const short8*)(WTsg + (ct * 16 + l15) * 384 + 256 + ks * 32 + lkb);
            #pragma unroll
            for (int m = 0; m < 4; ++m) accS[t][m] = MFMA(a[m], b, accS[t][m]);
        }
    }

    // scal epilogue: silu -> global
    #pragma unroll
    for (int t = 0; t < 2; ++t) {
        int col = (wave + t * 8) * 16 + l15;
        float bc = bias[col];
        #pragma unroll
        for (int m = 0; m < 4; ++m)
        #pragma unroll
        for (int i = 0; i < 4; ++i) {
            int n = n0 + m * 16 + rbase + i;
            if (n < N) {
                float sc = C0F * accS[t][m][i] + bc;
                out[(size_t)n * DIM_Hc + col] = sc / (1.f + __expf(-sc));
            }
        }
    }
    // gate -> sigmoid, stays in registers (gate col wave*16+l15 == vec u-tile col)
    float sgr[4][4];
    #pragma unroll
    for (int m = 0; m < 4; ++m)
    #pragma unroll
    for (int i = 0; i < 4; ++i) sgr[m][i] = 1.f / (1.f + __expf(-C0F * accS[2][m][i]));

    // ---------------- vec GEMMs: a1 (xs, K=256) + v2_k (xv planes, K=128 x3) ----------------
    f32x4 accA[4], accV[3][4];
    #pragma unroll
    for (int m = 0; m < 4; ++m) accA[m] = (f32x4){0,0,0,0};
    #pragma unroll
    for (int k = 0; k < 3; ++k)
    #pragma unroll
    for (int m = 0; m < 4; ++m) accV[k][m] = (f32x4){0,0,0,0};

    #pragma unroll
    for (int ks = 0; ks < 8; ++ks) {
        int kf = ks * 32 + lkb;
        short8 b = *(const short8*)(WTsv + (wave * 16 + l15) * 256 + ks * 32 + lkb);
        #pragma unroll
        for (int m = 0; m < 4; ++m) {
            short8 a = *(const short8*)(fbr + (((m * 16 + l15) * 1536 + kf * 2) ^ swzr));
            accA[m] = MFMA(a, b, accA[m]);
        }
    }
    #pragma unroll
    for (int ks = 0; ks < 4; ++ks) {
        short8 b = *(const short8*)(WTvs + (wave * 16 + l15) * 128 + ks * 32 + lkb);
        #pragma unroll
        for (int p = 0; p < 3; ++p) {
            int kf = 384 + 128 * p + ks * 32 + lkb;
            #pragma unroll
            for (int m = 0; m < 4; ++m) {
                short8 a = *(const short8*)(fbr + (((m * 16 + l15) * 1536 + kf * 2) ^ swzr));
                accV[p][m] = MFMA(a, b, accV[p][m]);
            }
        }
    }

    // ---------------- vec epilogue: vec = C0*(a1*pv + v2*ps) * sigmoid(gate) ----------------
    {
        int u = wave * 16 + l15;
        #pragma unroll
        for (int m = 0; m < 4; ++m)
        #pragma unroll
        for (int i = 0; i < 4; ++i) {
            int nl = m * 16 + rbase + i;
            int n = n0 + nl;
            if (n >= N) continue;
            float sg  = sgr[m][i];
            float ps  = pss[m][i];
            float pv0 = psv[nl * 4 + 1], pv1 = psv[nl * 4 + 2], pv2 = psv[nl * 4 + 3];
            float av = accA[m][i];
            size_t ob = (size_t)n * DIM_Hc + MUL_Sc + 3 * u;
            out[ob + 0] = C0F * (av * pv0 + accV[0][m][i] * ps) * sg;
            out[ob + 1] = C0F * (av * pv1 + accV[1][m][i] * ps) * sg;
            out[ob + 2] = C0F * (av * pv2 + accV[2][m][i] * ps) * sg;
        }
    }
}

extern "C" void kernel_launch(void* const* d_in, const int* in_sizes, int n_in,
                              void* d_out, int out_size, void* d_ws, size_t ws_size,
                              hipStream_t stream) {
    const float* din  = (const float*)d_in[0];
    const float* Wss  = (const float*)d_in[1];
    const float* Wvv  = (const float*)d_in[2];
    const float* Wssg = (const float*)d_in[3];
    const float* Wvvg = (const float*)d_in[4];
    const float* Wsv  = (const float*)d_in[5];
    const float* Wvs  = (const float*)d_in[6];
    const float* bias = (const float*)d_in[7];
    float* out = (float*)d_out;
    unsigned short* wt = (unsigned short*)d_ws;

    const size_t WT_BYTES = (size_t)(384 * 384 + 128 * 256 + 128 * 128) * 2;
    if (ws_size < WT_BYTES) return;

    int N = in_sizes[0] / IN_COLS;

    int prep_total = 384 * 384 + 128 * 256 + 128 * 128;
    prep_weights<<<(prep_total + 255) / 256, 256, 0, stream>>>(Wss, Wvv, Wssg, Wvvg, Wsv, Wvs, wt);

    int nblocks = (N + NT - 1) / NT;
    fused_main<<<nblocks, 512, 0, stream>>>(din, wt, bias, out, N);
}